// Round 1
// baseline (733.661 us; speedup 1.0000x reference)
//
#include <hip/hip_runtime.h>
#include <hip/hip_bf16.h>

// ---------------------------------------------------------------------------
// QLSTMCell on MI355X: fused [x|h]·[Wih|Whh]^T bf16 MFMA GEMM + hard-sigmoid cell
// Round 1: m97-structure (128x128 tile, global_load_lds w=16) baseline.
// ---------------------------------------------------------------------------

typedef __attribute__((ext_vector_type(8))) short short8;   // 8 x bf16 (4 VGPRs)
typedef __attribute__((ext_vector_type(4))) float f32x4;    // MFMA accum

#define B_SZ 4096
#define IN_SZ 2048
#define H_SZ 2048
#define K_SZ 4096      // IN + H
#define N_SZ 8192      // 4*H

typedef const __attribute__((address_space(1))) void gvoid_t;
typedef __attribute__((address_space(3))) void lvoid_t;

__device__ __forceinline__ void gload_lds16(const __hip_bfloat16* g, void* l) {
    // 16B per lane; LDS dest = wave-uniform base + lane*16 (HW rule)
    __builtin_amdgcn_global_load_lds((gvoid_t*)g, (lvoid_t*)l, 16, 0, 0);
}

// ---- fp32 -> bf16 conversion with [A | B] row-concat -----------------------
// out[r][0:2048] = cvt(a[r][:]), out[r][2048:4096] = cvt(b[r][:])
__global__ void cvt_concat_kernel(const float* __restrict__ a,
                                  const float* __restrict__ b,
                                  __hip_bfloat16* __restrict__ out,
                                  int total4)
{
    int i = blockIdx.x * blockDim.x + threadIdx.x;
    if (i >= total4) return;
    int idx = i << 2;
    int r = idx >> 12;       // / 4096
    int c = idx & 4095;
    const float* src = (c < IN_SZ) ? (a + (size_t)r * IN_SZ + c)
                                   : (b + (size_t)r * IN_SZ + (c - IN_SZ));
    float4 v = *reinterpret_cast<const float4*>(src);
    union { ushort4 u; __hip_bfloat16 h[4]; } p;
    p.h[0] = __float2bfloat16(v.x);
    p.h[1] = __float2bfloat16(v.y);
    p.h[2] = __float2bfloat16(v.z);
    p.h[3] = __float2bfloat16(v.w);
    *reinterpret_cast<ushort4*>(out + idx) = p.u;
}

// ---- NT GEMM: C[M][N] = A[M][K] * Bw[N][K]^T  (both K-contiguous, bf16) ----
// m97 structure: 128x128 tile, BK=32, 4 waves (2x2), 4x4 16x16x32 frags/wave.
__global__ __launch_bounds__(256)
void gemm_bt_kernel(const __hip_bfloat16* __restrict__ A,
                    const __hip_bfloat16* __restrict__ Bw,
                    float* __restrict__ C)
{
    constexpr int BM = 128, BN = 128, BK = 32;
    constexpr int NBM = B_SZ / BM;   // 32
    constexpr int NBN = N_SZ / BN;   // 64
    constexpr int NWG = NBM * NBN;   // 2048 (multiple of 8 -> simple swizzle ok)

    __shared__ __align__(16) __hip_bfloat16 Alds[BM * BK];  // 8 KB
    __shared__ __align__(16) __hip_bfloat16 Blds[BN * BK];  // 8 KB

    const int tid  = threadIdx.x;
    const int wave = tid >> 6;
    const int lane = tid & 63;
    const int wr = wave >> 1, wc = wave & 1;   // 2x2 wave grid, 64x64 each

    // XCD-aware bijective swizzle (NWG % 8 == 0)
    constexpr int CPX = NWG / 8;
    int bid = blockIdx.x;
    int swz = (bid & 7) * CPX + (bid >> 3);
    int bm = swz / NBN, bn = swz % NBN;

    const __hip_bfloat16* Ag = A  + (size_t)bm * BM * K_SZ;
    const __hip_bfloat16* Bg = Bw + (size_t)bn * BN * K_SZ;

    f32x4 acc[4][4];
#pragma unroll
    for (int m = 0; m < 4; ++m)
#pragma unroll
        for (int n = 0; n < 4; ++n)
            acc[m][n] = f32x4{0.f, 0.f, 0.f, 0.f};

    // staging slots: slot s in [0,512): row = s>>2, 16B-chunk = s&3
    const int r0  = tid >> 2;
    const int kq0 = tid & 3;
    const int r1  = r0 + 64;            // slot tid+256

    const int fkq = lane >> 4;          // k-quarter for fragments
    const int fr  = lane & 15;          // row/col within fragment

    for (int kt = 0; kt < K_SZ; kt += BK) {
        gload_lds16(Ag + (size_t)r0 * K_SZ + kt + kq0 * 8, (char*)Alds + wave * 1024);
        gload_lds16(Ag + (size_t)r1 * K_SZ + kt + kq0 * 8, (char*)Alds + wave * 1024 + 4096);
        gload_lds16(Bg + (size_t)r0 * K_SZ + kt + kq0 * 8, (char*)Blds + wave * 1024);
        gload_lds16(Bg + (size_t)r1 * K_SZ + kt + kq0 * 8, (char*)Blds + wave * 1024 + 4096);
        __syncthreads();   // drains vmcnt before reads

        const short8* Af = reinterpret_cast<const short8*>(Alds);
        const short8* Bf = reinterpret_cast<const short8*>(Blds);
        short8 av[4], bv[4];
#pragma unroll
        for (int m = 0; m < 4; ++m)
            av[m] = Af[(wr * 64 + m * 16 + fr) * 4 + fkq];
#pragma unroll
        for (int n = 0; n < 4; ++n)
            bv[n] = Bf[(wc * 64 + n * 16 + fr) * 4 + fkq];
#pragma unroll
        for (int m = 0; m < 4; ++m)
#pragma unroll
            for (int n = 0; n < 4; ++n)
                acc[m][n] = __builtin_amdgcn_mfma_f32_16x16x32_bf16(av[m], bv[n], acc[m][n], 0, 0, 0);
        __syncthreads();   // LDS reuse next iter
    }

    // C/D layout (m89-verified): col = lane&15, row = (lane>>4)*4 + i
    float* Cb = C + (size_t)(bm * BM) * N_SZ + bn * BN;
#pragma unroll
    for (int m = 0; m < 4; ++m)
#pragma unroll
        for (int n = 0; n < 4; ++n) {
            int col  = wc * 64 + n * 16 + fr;
            int row0 = wr * 64 + m * 16 + fkq * 4;
#pragma unroll
            for (int i = 0; i < 4; ++i)
                Cb[(size_t)(row0 + i) * N_SZ + col] = acc[m][n][i];
        }
}

// ---- elementwise LSTM cell -------------------------------------------------
__device__ __forceinline__ float hsig(float x) {
    return fminf(fmaxf(x * (1.0f / 6.0f) + 0.5f, 0.0f), 1.0f);
}
__device__ __forceinline__ float htanh(float x) {
    return fminf(fmaxf(x, -1.0f), 1.0f);
}

__global__ void cell_kernel(const float* __restrict__ G,     // [B][8192] gates f,i,o,g
                            const float* __restrict__ c0,    // [B][2048]
                            const float* __restrict__ bias,  // [8192]
                            float* __restrict__ out)         // h1 [B][2048] then c1
{
    int t = (blockIdx.x * blockDim.x + threadIdx.x) << 2;
    int bb = t >> 11;        // / 2048
    int j  = t & 2047;
    const float* Gr = G + (size_t)bb * N_SZ + j;
    float4 f4 = *(const float4*)(Gr);
    float4 i4 = *(const float4*)(Gr + 2048);
    float4 o4 = *(const float4*)(Gr + 4096);
    float4 g4 = *(const float4*)(Gr + 6144);
    float4 bf4 = *(const float4*)(bias + j);
    float4 bi4 = *(const float4*)(bias + 2048 + j);
    float4 bo4 = *(const float4*)(bias + 4096 + j);
    float4 bg4 = *(const float4*)(bias + 6144 + j);
    float4 c4  = *(const float4*)(c0 + (size_t)bb * H_SZ + j);

    float4 h1v, c1v;
    float* h1p = (float*)&h1v;
    float* c1p = (float*)&c1v;
#pragma unroll
    for (int q = 0; q < 4; ++q) {
        float f = ((const float*)&f4)[q] + ((const float*)&bf4)[q];
        float i = ((const float*)&i4)[q] + ((const float*)&bi4)[q];
        float o = ((const float*)&o4)[q] + ((const float*)&bo4)[q];
        float g = ((const float*)&g4)[q] + ((const float*)&bg4)[q];
        float c = ((const float*)&c4)[q];
        float cn = hsig(f) * c + hsig(i) * htanh(g);
        c1p[q] = cn;
        h1p[q] = hsig(o) * htanh(cn);
    }
    *(float4*)(out + (size_t)bb * H_SZ + j) = h1v;
    *(float4*)(out + (size_t)B_SZ * H_SZ + (size_t)bb * H_SZ + j) = c1v;
}

// ---------------------------------------------------------------------------
extern "C" void kernel_launch(void* const* d_in, const int* in_sizes, int n_in,
                              void* d_out, int out_size, void* d_ws, size_t ws_size,
                              hipStream_t stream)
{
    const float* x   = (const float*)d_in[0];  // [4096,2048]
    const float* h0  = (const float*)d_in[1];  // [4096,2048]
    const float* c0  = (const float*)d_in[2];  // [4096,2048]
    const float* Wih = (const float*)d_in[3];  // [8192,2048]
    const float* Whh = (const float*)d_in[4];  // [8192,2048]
    const float* bhh = (const float*)d_in[5];  // [8192]
    float* out = (float*)d_out;                // h1 (8M) ++ c1 (8M) fp32

    // workspace layout: X' bf16 32MB | W' bf16 64MB | gates fp32 128MB = 224MB
    const size_t NEED = (size_t)224 * 1024 * 1024;
    if (ws_size < NEED) return;  // bench will surface this; adapt next round
    char* ws = (char*)d_ws;
    __hip_bfloat16* Xp = (__hip_bfloat16*)ws;
    __hip_bfloat16* Wp = (__hip_bfloat16*)(ws + (size_t)32 * 1024 * 1024);
    float*          Gt = (float*)(ws + (size_t)96 * 1024 * 1024);

    int t4x = B_SZ * K_SZ / 4;   // 4M quads
    cvt_concat_kernel<<<t4x / 256, 256, 0, stream>>>(x, h0, Xp, t4x);
    int t4w = N_SZ * K_SZ / 4;   // 8M quads
    cvt_concat_kernel<<<t4w / 256, 256, 0, stream>>>(Wih, Whh, Wp, t4w);

    gemm_bt_kernel<<<2048, 256, 0, stream>>>(Xp, Wp, Gt);

    int cquads = B_SZ * H_SZ / 4;   // 2M threads
    cell_kernel<<<cquads / 256, 256, 0, stream>>>(Gt, c0, bhh, out);
}

// Round 6
// 579.133 us; speedup vs baseline: 1.2668x; 1.2668x over previous
//
#include <hip/hip_runtime.h>
#include <hip/hip_bf16.h>

// ---------------------------------------------------------------------------
// QLSTMCell MI355X round 6 — DE-RISKED after "container failed twice":
//  - keeps the algorithmic wins: gate-interleaved W' permutation + fused
//    LSTM-cell epilogue (no gate matrix, no cell kernel)
//  - reverts to the R1-verified __syncthreads 2-barrier schedule (cannot
//    hang); parameter deltas only: BK 32->64, T2 chunk^row LDS swizzle
//  - 128x128 tile, 4 waves, single LDS buffer (32 KB), XCD swizzle
// ---------------------------------------------------------------------------

typedef __attribute__((ext_vector_type(8))) short short8;   // 8 x bf16
typedef __attribute__((ext_vector_type(4))) float f32x4;    // MFMA accum

#define B_SZ 4096
#define K_SZ 4096      // IN + H
#define N_SZ 8192      // 4*H
#define H_SZ 2048

typedef const __attribute__((address_space(1))) void gvoid_t;
typedef __attribute__((address_space(3))) void lvoid_t;

__device__ __forceinline__ void gload_lds16(const __hip_bfloat16* g, void* l) {
    // LDS dest is wave-uniform base; HW adds lane*16
    __builtin_amdgcn_global_load_lds((gvoid_t*)g, (lvoid_t*)l, 16, 0, 0);
}

__device__ __forceinline__ float hsig(float x) {
    return fminf(fmaxf(x * (1.0f / 6.0f) + 0.5f, 0.0f), 1.0f);
}
__device__ __forceinline__ float htanh(float x) {
    return fminf(fmaxf(x, -1.0f), 1.0f);
}

// ---- fp32 -> bf16 with [A | B] row-concat (for X' = [x | h]) ---------------
__global__ void cvt_concat_kernel(const float* __restrict__ a,
                                  const float* __restrict__ b,
                                  __hip_bfloat16* __restrict__ out,
                                  int total4)
{
    int i = blockIdx.x * blockDim.x + threadIdx.x;
    if (i >= total4) return;
    int idx = i << 2;
    int r = idx >> 12;       // / 4096
    int c = idx & 4095;
    const float* src = (c < 2048) ? (a + (size_t)r * 2048 + c)
                                  : (b + (size_t)r * 2048 + (c - 2048));
    float4 v = *reinterpret_cast<const float4*>(src);
    union { ushort4 u; __hip_bfloat16 h[4]; } p;
    p.h[0] = __float2bfloat16(v.x);
    p.h[1] = __float2bfloat16(v.y);
    p.h[2] = __float2bfloat16(v.z);
    p.h[3] = __float2bfloat16(v.w);
    *reinterpret_cast<ushort4*>(out + idx) = p.u;
}

// ---- W' builder: bf16, [Wih | Whh] col-concat, gate-interleaved row perm ---
// out row r <- original gate row: gate=(r>>4)&3, j=(r>>6)*16+(r&15),
// srow = gate*2048 + j. GEMM col c = bn*128 + wc*64 + n*16 + fr then has
// bits4-5 == n == gate and j == (bn*2+wc)*16 + fr (lane-local).
__global__ void cvt_w_perm_kernel(const float* __restrict__ wih,
                                  const float* __restrict__ whh,
                                  __hip_bfloat16* __restrict__ out,
                                  int total4)
{
    int i = blockIdx.x * blockDim.x + threadIdx.x;
    if (i >= total4) return;
    int idx = i << 2;
    int r = idx >> 12;        // out row 0..8191
    int c = idx & 4095;       // col
    int gate = (r >> 4) & 3;
    int j = ((r >> 6) << 4) | (r & 15);
    int srow = gate * 2048 + j;
    const float* src = (c < 2048) ? (wih + (size_t)srow * 2048 + c)
                                  : (whh + (size_t)srow * 2048 + (c - 2048));
    float4 v = *reinterpret_cast<const float4*>(src);
    union { ushort4 u; __hip_bfloat16 h[4]; } p;
    p.h[0] = __float2bfloat16(v.x);
    p.h[1] = __float2bfloat16(v.y);
    p.h[2] = __float2bfloat16(v.z);
    p.h[3] = __float2bfloat16(v.w);
    *reinterpret_cast<ushort4*>(out + idx) = p.u;
}

// ---- fused GEMM + LSTM cell (safe __syncthreads schedule) ------------------
// C[4096][8192] = X'[4096][4096] * W'[8192][4096]^T; epilogue applies cell.
__global__ __launch_bounds__(256)
void gemm_fused_kernel(const __hip_bfloat16* __restrict__ A,
                       const __hip_bfloat16* __restrict__ Bw,
                       const float* __restrict__ c0,
                       const float* __restrict__ bias,
                       float* __restrict__ out)
{
    constexpr int BM = 128, BN = 128, BK = 64;
    constexpr int NBM = B_SZ / BM;   // 32
    constexpr int NBN = N_SZ / BN;   // 64
    constexpr int NWG = NBM * NBN;   // 2048 (%8==0)
    constexpr int ABYTES = BM * BK * 2;  // 16384

    __shared__ __align__(16) char lds[2 * ABYTES];   // A (16K) + B (16K)

    const int tid  = threadIdx.x;
    const int wave = tid >> 6;
    const int lane = tid & 63;
    const int wr = wave >> 1, wc = wave & 1;   // 2x2 wave grid, 64x64 each
    const int fr  = lane & 15;
    const int fkq = lane >> 4;

    // XCD-aware bijective swizzle
    int bid = blockIdx.x;
    int swz = (bid & 7) * (NWG / 8) + (bid >> 3);
    int bm = swz / NBN, bn = swz % NBN;

    // ---- staging (linear LDS dest; inverse-swizzled global source) ---------
    // stripe s: row = s*32 + (tid>>3), physical chunk = tid&7,
    // logical chunk = ch ^ (row&7); (s*32)%8==0 so row&7 == (tid>>3)&7.
    const int rs = tid >> 3;              // 0..31
    const int ch = tid & 7;
    const int lch = ch ^ (rs & 7);
    const __hip_bfloat16* pa = A  + (size_t)(bm * BM + rs) * K_SZ + lch * 8;
    const __hip_bfloat16* pb = Bw + (size_t)(bn * BN + rs) * K_SZ + lch * 8;

    // ---- swizzled ds_read byte offsets (kk=0); kk=1 is ^64 -----------------
    int a_off[4], b_off[4];
#pragma unroll
    for (int m = 0; m < 4; ++m) {
        int row = wr * 64 + m * 16 + fr;
        a_off[m] = row * 128 + ((fkq ^ (row & 7)) << 4);
    }
#pragma unroll
    for (int n = 0; n < 4; ++n) {
        int row = wc * 64 + n * 16 + fr;
        b_off[n] = row * 128 + ((fkq ^ (row & 7)) << 4);
    }

    f32x4 acc[4][4];
#pragma unroll
    for (int m = 0; m < 4; ++m)
#pragma unroll
        for (int n = 0; n < 4; ++n)
            acc[m][n] = f32x4{0.f, 0.f, 0.f, 0.f};

    for (int kt = 0; kt < K_SZ; kt += BK) {
#pragma unroll
        for (int s = 0; s < 4; ++s)
            gload_lds16(pa + (size_t)s * 32 * K_SZ + kt, lds + s * 4096 + wave * 1024);
#pragma unroll
        for (int s = 0; s < 4; ++s)
            gload_lds16(pb + (size_t)s * 32 * K_SZ + kt, lds + ABYTES + s * 4096 + wave * 1024);
        __syncthreads();   // compiler drains vmcnt before barrier

        short8 av[4], bv[4];
#pragma unroll
        for (int kk = 0; kk < 2; ++kk) {
            const int x = kk * 64;   // chunk bit 2 flip == byte ^ 64
#pragma unroll
            for (int m = 0; m < 4; ++m) av[m] = *(const short8*)(lds + (a_off[m] ^ x));
#pragma unroll
            for (int n = 0; n < 4; ++n) bv[n] = *(const short8*)(lds + ABYTES + (b_off[n] ^ x));
#pragma unroll
            for (int m = 0; m < 4; ++m)
#pragma unroll
                for (int n = 0; n < 4; ++n)
                    acc[m][n] = __builtin_amdgcn_mfma_f32_16x16x32_bf16(av[m], bv[n], acc[m][n], 0, 0, 0);
        }
        __syncthreads();   // LDS reuse next iter
    }

    // ---- fused LSTM-cell epilogue (n-fragment == gate: 0=f,1=i,2=o,3=g) ----
    const int jj = (bn * 2 + wc) * 16 + fr;          // 0..2047
    const float bf = bias[jj];
    const float bi = bias[2048 + jj];
    const float bo = bias[4096 + jj];
    const float bg = bias[6144 + jj];
    const int row0 = bm * BM + wr * 64 + fkq * 4;
    float* h1out = out;
    float* c1out = out + (size_t)B_SZ * H_SZ;
#pragma unroll
    for (int m = 0; m < 4; ++m) {
#pragma unroll
        for (int i = 0; i < 4; ++i) {
            int r = row0 + m * 16 + i;
            float c0v = c0[(size_t)r * H_SZ + jj];
            float f  = acc[m][0][i] + bf;
            float ig = acc[m][1][i] + bi;
            float o  = acc[m][2][i] + bo;
            float g  = acc[m][3][i] + bg;
            float cn = hsig(f) * c0v + hsig(ig) * htanh(g);
            h1out[(size_t)r * H_SZ + jj] = hsig(o) * htanh(cn);
            c1out[(size_t)r * H_SZ + jj] = cn;
        }
    }
}

// ---------------------------------------------------------------------------
extern "C" void kernel_launch(void* const* d_in, const int* in_sizes, int n_in,
                              void* d_out, int out_size, void* d_ws, size_t ws_size,
                              hipStream_t stream)
{
    const float* x   = (const float*)d_in[0];  // [4096,2048]
    const float* h0  = (const float*)d_in[1];  // [4096,2048]
    const float* c0  = (const float*)d_in[2];  // [4096,2048]
    const float* Wih = (const float*)d_in[3];  // [8192,2048]
    const float* Whh = (const float*)d_in[4];  // [8192,2048]
    const float* bhh = (const float*)d_in[5];  // [8192]
    float* out = (float*)d_out;                // h1 (8M) ++ c1 (8M) fp32

    // workspace: X' bf16 32MB | W' bf16 64MB
    if (ws_size < (size_t)96 * 1024 * 1024) return;
    char* ws = (char*)d_ws;
    __hip_bfloat16* Xp = (__hip_bfloat16*)ws;
    __hip_bfloat16* Wp = (__hip_bfloat16*)(ws + (size_t)32 * 1024 * 1024);

    int t4x = B_SZ * K_SZ / 4;   // 4M quads
    cvt_concat_kernel<<<t4x / 256, 256, 0, stream>>>(x, h0, Xp, t4x);
    int t4w = N_SZ * K_SZ / 4;   // 8M quads
    cvt_w_perm_kernel<<<t4w / 256, 256, 0, stream>>>(Wih, Whh, Wp, t4w);

    gemm_fused_kernel<<<2048, 256, 0, stream>>>(Xp, Wp, c0, bhh, out);
}

// Round 7
// 480.404 us; speedup vs baseline: 1.5272x; 1.2055x over previous
//
#include <hip/hip_runtime.h>
#include <hip/hip_bf16.h>

// ---------------------------------------------------------------------------
// QLSTMCell MI355X round 7:
//  - carries R6-verified: gate-permuted W' + fused cell epilogue (WRITE=65MB,
//    bank-conflict=0 measured)
//  - single delta: 256x256xBK64 8-wave counted-vmcnt phase schedule (T3+T4),
//    4 phases/K-tile (one C-quadrant each, 16 MFMA), dbuf LDS 128KB dynamic.
// vmcnt LEDGER (per wave; 2 gloads per stage macro pair):
//   stage order per K-tile t (into buf[(t+1)&1], for tile t+1):
//     p0: A-half0(2)  p1: B-half0(2)  p2: A-half1(2)  p3: B-half1(2)
//   p0-end: outstanding = A1(t),B1(t),A0(t+1) = 6 -> vmcnt(2) retires A1,B1(t)
//           (needed by p1/p2 reads), keeps A0(t+1) in flight
//   p3-end: outstanding = A0,B0,A1,B1(t+1) = 8 -> vmcnt(4) retires A0,B0(t+1)
//           (needed by next p0 reads)
//   last tile (no stages): p0-end vmcnt(0) drains the final A1,B1.
// ---------------------------------------------------------------------------

typedef __attribute__((ext_vector_type(8))) short short8;   // 8 x bf16
typedef __attribute__((ext_vector_type(4))) float f32x4;    // MFMA accum

#define B_SZ 4096
#define K_SZ 4096      // IN + H
#define N_SZ 8192      // 4*H
#define H_SZ 2048

typedef const __attribute__((address_space(1))) void gvoid_t;
typedef __attribute__((address_space(3))) void lvoid_t;

__device__ __forceinline__ void gload_lds16(const __hip_bfloat16* g, void* l) {
    // LDS dest is wave-uniform base; HW adds lane*16
    __builtin_amdgcn_global_load_lds((gvoid_t*)g, (lvoid_t*)l, 16, 0, 0);
}

__device__ __forceinline__ float hsig(float x) {
    return fminf(fmaxf(x * (1.0f / 6.0f) + 0.5f, 0.0f), 1.0f);
}
__device__ __forceinline__ float htanh(float x) {
    return fminf(fmaxf(x, -1.0f), 1.0f);
}

// ---- fp32 -> bf16 with [A | B] row-concat (for X' = [x | h]) ---------------
__global__ void cvt_concat_kernel(const float* __restrict__ a,
                                  const float* __restrict__ b,
                                  __hip_bfloat16* __restrict__ out,
                                  int total4)
{
    int i = blockIdx.x * blockDim.x + threadIdx.x;
    if (i >= total4) return;
    int idx = i << 2;
    int r = idx >> 12;       // / 4096
    int c = idx & 4095;
    const float* src = (c < 2048) ? (a + (size_t)r * 2048 + c)
                                  : (b + (size_t)r * 2048 + (c - 2048));
    float4 v = *reinterpret_cast<const float4*>(src);
    union { ushort4 u; __hip_bfloat16 h[4]; } p;
    p.h[0] = __float2bfloat16(v.x);
    p.h[1] = __float2bfloat16(v.y);
    p.h[2] = __float2bfloat16(v.z);
    p.h[3] = __float2bfloat16(v.w);
    *reinterpret_cast<ushort4*>(out + idx) = p.u;
}

// ---- W' builder: gate-interleaved row perm for the 256-wide tile -----------
// GEMM col c (= out row r): bits [0:3]=fr, bit4=nf, bits[5:6]=wcol, bit7=nh,
// bits[8+]=bn. Gate = nh*2+nf = acc n-index; j = fr | wcol<<4 | bn<<6.
__global__ void cvt_w_perm_kernel(const float* __restrict__ wih,
                                  const float* __restrict__ whh,
                                  __hip_bfloat16* __restrict__ out,
                                  int total4)
{
    int i = blockIdx.x * blockDim.x + threadIdx.x;
    if (i >= total4) return;
    int idx = i << 2;
    int r = idx >> 12;        // out row 0..8191
    int c = idx & 4095;       // col
    int gate = (((r >> 7) & 1) << 1) | ((r >> 4) & 1);
    int j = (r & 15) | (((r >> 5) & 3) << 4) | ((r >> 8) << 6);
    int srow = gate * 2048 + j;
    const float* src = (c < 2048) ? (wih + (size_t)srow * 2048 + c)
                                  : (whh + (size_t)srow * 2048 + (c - 2048));
    float4 v = *reinterpret_cast<const float4*>(src);
    union { ushort4 u; __hip_bfloat16 h[4]; } p;
    p.h[0] = __float2bfloat16(v.x);
    p.h[1] = __float2bfloat16(v.y);
    p.h[2] = __float2bfloat16(v.z);
    p.h[3] = __float2bfloat16(v.w);
    *reinterpret_cast<ushort4*>(out + idx) = p.u;
}

// ---- fused GEMM + LSTM cell, 8-wave 256^2 counted-vmcnt schedule -----------
__global__ __launch_bounds__(512, 2)
void gemm_fused_kernel(const __hip_bfloat16* __restrict__ A,
                       const __hip_bfloat16* __restrict__ Bw,
                       const float* __restrict__ c0,
                       const float* __restrict__ bias,
                       float* __restrict__ out)
{
    constexpr int BK = 64;
    constexpr int NT = K_SZ / BK;            // 64 K-tiles
    constexpr int NWG = (B_SZ / 256) * (N_SZ / 256);  // 16*32 = 512
    constexpr int TILEB = 65536;             // A 32KB + B 32KB per buffer

    extern __shared__ __align__(16) char lds[];   // 2 * TILEB = 128KB dynamic

    const int tid  = threadIdx.x;
    const int wave = tid >> 6;
    const int lane = tid & 63;
    const int wrow = wave >> 2;        // 0..1
    const int wcol = wave & 3;         // 0..3
    const int fr   = lane & 15;
    const int fkq  = lane >> 4;

    // XCD-aware bijective swizzle (NWG = 512, %8==0)
    int bid = blockIdx.x;
    int swz = (bid & 7) * (NWG / 8) + (bid >> 3);
    int bm = swz >> 5;                 // 0..15
    int bn = swz & 31;                 // 0..31

    // ---- staging (linear LDS dest; inverse-swizzled global source) ---------
    const int rs  = tid >> 3;          // 0..63 row within 64-row stage
    const int ch  = tid & 7;
    const int lch = ch ^ (rs & 7);
    const __hip_bfloat16* pa = A  + (size_t)(bm * 256 + rs) * K_SZ + lch * 8;
    const __hip_bfloat16* pb = Bw + (size_t)(bn * 256 + rs) * K_SZ + lch * 8;

#define STG_A(bufn, kt, srow) \
    gload_lds16(pa + (size_t)(srow) * K_SZ + (kt), (bufn) + (srow) * 128 + wave * 1024)
#define STG_B(bufn, kt, srow) \
    gload_lds16(pb + (size_t)(srow) * K_SZ + (kt), (bufn) + 32768 + (srow) * 128 + wave * 1024)

    // ---- swizzled ds_read byte offsets (ks=0); ks=1 is ^64, mh/nh is +16384
    // A rows: mh*128 + wrow*64 + mf*16 + fr ; B rows: nh*128 + wcol*32 + nf*16 + fr
    int a_off[4], b_off[2];
#pragma unroll
    for (int mf = 0; mf < 4; ++mf) {
        int row = wrow * 64 + mf * 16 + fr;
        a_off[mf] = row * 128 + ((fkq ^ (row & 7)) << 4);
    }
#pragma unroll
    for (int nf = 0; nf < 2; ++nf) {
        int row = wcol * 32 + nf * 16 + fr;
        b_off[nf] = row * 128 + ((fkq ^ (row & 7)) << 4);
    }

    f32x4 acc[8][4];
#pragma unroll
    for (int m = 0; m < 8; ++m)
#pragma unroll
        for (int n = 0; n < 4; ++n)
            acc[m][n] = f32x4{0.f, 0.f, 0.f, 0.f};

    // ---- prologue: stage tile 0 fully (8 gloads/wave, order A0 B0 A1 B1) ---
    {
        char* b0 = lds;
        STG_A(b0, 0, 0);   STG_A(b0, 0, 64);    // A-half0
        STG_B(b0, 0, 0);   STG_B(b0, 0, 64);    // B-half0
        STG_A(b0, 0, 128); STG_A(b0, 0, 192);   // A-half1
        STG_B(b0, 0, 128); STG_B(b0, 0, 192);   // B-half1
    }
    asm volatile("s_waitcnt vmcnt(4)" ::: "memory");   // A0,B0 resident
    asm volatile("s_barrier" ::: "memory");

    short8 av[4][2], bv[2][2];

#pragma unroll 1
    for (int t = 0; t < NT; ++t) {
        char* bufc = lds + (t & 1) * TILEB;
        char* bufn = lds + ((t + 1) & 1) * TILEB;
        const char* Ab = bufc;
        const char* Bb = bufc + 32768;
        const int ktn = (t + 1) * BK;
        const bool st = (t + 1 < NT);

        // ============ phase 0: quadrant (mh0, nh0) ============
#pragma unroll
        for (int mf = 0; mf < 4; ++mf)
#pragma unroll
            for (int ks = 0; ks < 2; ++ks)
                av[mf][ks] = *(const short8*)(Ab + (a_off[mf] ^ (ks << 6)));
#pragma unroll
        for (int nf = 0; nf < 2; ++nf)
#pragma unroll
            for (int ks = 0; ks < 2; ++ks)
                bv[nf][ks] = *(const short8*)(Bb + (b_off[nf] ^ (ks << 6)));
        if (st) { STG_A(bufn, ktn, 0); STG_A(bufn, ktn, 64); }
        asm volatile("s_barrier" ::: "memory");
        asm volatile("s_waitcnt lgkmcnt(0)" ::: "memory");
        __builtin_amdgcn_sched_barrier(0);
        __builtin_amdgcn_s_setprio(1);
#pragma unroll
        for (int mf = 0; mf < 4; ++mf)
#pragma unroll
            for (int nf = 0; nf < 2; ++nf)
#pragma unroll
                for (int ks = 0; ks < 2; ++ks)
                    acc[mf][nf] = __builtin_amdgcn_mfma_f32_16x16x32_bf16(av[mf][ks], bv[nf][ks], acc[mf][nf], 0, 0, 0);
        __builtin_amdgcn_s_setprio(0);
        if (st) asm volatile("s_waitcnt vmcnt(2)" ::: "memory");
        else    asm volatile("s_waitcnt vmcnt(0)" ::: "memory");
        asm volatile("s_barrier" ::: "memory");

        // ============ phase 1: quadrant (mh0, nh1) ============
#pragma unroll
        for (int nf = 0; nf < 2; ++nf)
#pragma unroll
            for (int ks = 0; ks < 2; ++ks)
                bv[nf][ks] = *(const short8*)(Bb + 16384 + (b_off[nf] ^ (ks << 6)));
        if (st) { STG_B(bufn, ktn, 0); STG_B(bufn, ktn, 64); }
        asm volatile("s_barrier" ::: "memory");
        asm volatile("s_waitcnt lgkmcnt(0)" ::: "memory");
        __builtin_amdgcn_sched_barrier(0);
        __builtin_amdgcn_s_setprio(1);
#pragma unroll
        for (int mf = 0; mf < 4; ++mf)
#pragma unroll
            for (int nf = 0; nf < 2; ++nf)
#pragma unroll
                for (int ks = 0; ks < 2; ++ks)
                    acc[mf][2 + nf] = __builtin_amdgcn_mfma_f32_16x16x32_bf16(av[mf][ks], bv[nf][ks], acc[mf][2 + nf], 0, 0, 0);
        __builtin_amdgcn_s_setprio(0);
        asm volatile("s_barrier" ::: "memory");

        // ============ phase 2: quadrant (mh1, nh0) ============
#pragma unroll
        for (int mf = 0; mf < 4; ++mf)
#pragma unroll
            for (int ks = 0; ks < 2; ++ks)
                av[mf][ks] = *(const short8*)(Ab + 16384 + (a_off[mf] ^ (ks << 6)));
#pragma unroll
        for (int nf = 0; nf < 2; ++nf)
#pragma unroll
            for (int ks = 0; ks < 2; ++ks)
                bv[nf][ks] = *(const short8*)(Bb + (b_off[nf] ^ (ks << 6)));
        if (st) { STG_A(bufn, ktn, 128); STG_A(bufn, ktn, 192); }
        asm volatile("s_barrier" ::: "memory");
        asm volatile("s_waitcnt lgkmcnt(0)" ::: "memory");
        __builtin_amdgcn_sched_barrier(0);
        __builtin_amdgcn_s_setprio(1);
#pragma unroll
        for (int mf = 0; mf < 4; ++mf)
#pragma unroll
            for (int nf = 0; nf < 2; ++nf)
#pragma unroll
                for (int ks = 0; ks < 2; ++ks)
                    acc[4 + mf][nf] = __builtin_amdgcn_mfma_f32_16x16x32_bf16(av[mf][ks], bv[nf][ks], acc[4 + mf][nf], 0, 0, 0);
        __builtin_amdgcn_s_setprio(0);
        asm volatile("s_barrier" ::: "memory");

        // ============ phase 3: quadrant (mh1, nh1) ============
#pragma unroll
        for (int nf = 0; nf < 2; ++nf)
#pragma unroll
            for (int ks = 0; ks < 2; ++ks)
                bv[nf][ks] = *(const short8*)(Bb + 16384 + (b_off[nf] ^ (ks << 6)));
        if (st) { STG_B(bufn, ktn, 128); STG_B(bufn, ktn, 192); }
        asm volatile("s_barrier" ::: "memory");
        asm volatile("s_waitcnt lgkmcnt(0)" ::: "memory");
        __builtin_amdgcn_sched_barrier(0);
        __builtin_amdgcn_s_setprio(1);
#pragma unroll
        for (int mf = 0; mf < 4; ++mf)
#pragma unroll
            for (int nf = 0; nf < 2; ++nf)
#pragma unroll
                for (int ks = 0; ks < 2; ++ks)
                    acc[4 + mf][2 + nf] = __builtin_amdgcn_mfma_f32_16x16x32_bf16(av[mf][ks], bv[nf][ks], acc[4 + mf][2 + nf], 0, 0, 0);
        __builtin_amdgcn_s_setprio(0);
        if (st) asm volatile("s_waitcnt vmcnt(4)" ::: "memory");
        asm volatile("s_barrier" ::: "memory");
    }
#undef STG_A
#undef STG_B

    // ---- fused LSTM-cell epilogue (acc n-index == gate: 0=f,1=i,2=o,3=g) ---
    const int jj = bn * 64 + wcol * 16 + fr;         // 0..2047
    const float bf = bias[jj];
    const float bi = bias[2048 + jj];
    const float bo = bias[4096 + jj];
    const float bg = bias[6144 + jj];
    float* h1out = out;
    float* c1out = out + (size_t)B_SZ * H_SZ;
#pragma unroll
    for (int mh = 0; mh < 2; ++mh)
#pragma unroll
        for (int mf = 0; mf < 4; ++mf) {
            const int m = mh * 4 + mf;
            const int row0 = bm * 256 + mh * 128 + wrow * 64 + mf * 16 + fkq * 4;
#pragma unroll
            for (int i = 0; i < 4; ++i) {
                int r = row0 + i;
                float c0v = c0[(size_t)r * H_SZ + jj];
                float f  = acc[m][0][i] + bf;
                float ig = acc[m][1][i] + bi;
                float o  = acc[m][2][i] + bo;
                float g  = acc[m][3][i] + bg;
                float cn = hsig(f) * c0v + hsig(ig) * htanh(g);
                h1out[(size_t)r * H_SZ + jj] = hsig(o) * htanh(cn);
                c1out[(size_t)r * H_SZ + jj] = cn;
            }
        }
}

// ---------------------------------------------------------------------------
extern "C" void kernel_launch(void* const* d_in, const int* in_sizes, int n_in,
                              void* d_out, int out_size, void* d_ws, size_t ws_size,
                              hipStream_t stream)
{
    const float* x   = (const float*)d_in[0];  // [4096,2048]
    const float* h0  = (const float*)d_in[1];  // [4096,2048]
    const float* c0  = (const float*)d_in[2];  // [4096,2048]
    const float* Wih = (const float*)d_in[3];  // [8192,2048]
    const float* Whh = (const float*)d_in[4];  // [8192,2048]
    const float* bhh = (const float*)d_in[5];  // [8192]
    float* out = (float*)d_out;                // h1 (8M) ++ c1 (8M) fp32

    // workspace: X' bf16 32MB | W' bf16 64MB
    if (ws_size < (size_t)96 * 1024 * 1024) return;
    char* ws = (char*)d_ws;
    __hip_bfloat16* Xp = (__hip_bfloat16*)ws;
    __hip_bfloat16* Wp = (__hip_bfloat16*)(ws + (size_t)32 * 1024 * 1024);

    int t4x = B_SZ * K_SZ / 4;   // 4M quads
    cvt_concat_kernel<<<t4x / 256, 256, 0, stream>>>(x, h0, Xp, t4x);
    int t4w = N_SZ * K_SZ / 4;   // 8M quads
    cvt_w_perm_kernel<<<t4w / 256, 256, 0, stream>>>(Wih, Whh, Wp, t4w);

    gemm_fused_kernel<<<512, 512, 131072, stream>>>(Xp, Wp, c0, bhh, out);
}

// Round 9
// 467.228 us; speedup vs baseline: 1.5702x; 1.0282x over previous
//
#include <hip/hip_runtime.h>
#include <hip/hip_bf16.h>

// ---------------------------------------------------------------------------
// QLSTMCell MI355X round 9 (= round 8 with cvt8_store compile fix):
//  - 256x256xBK64 8-wave 4-phase counted-vmcnt schedule, gate-permuted W',
//    fused cell epilogue (R7: 992 TF, conflicts=0)
//  - delta 1: dedupe B ds_reads (32->24 b128/wave/K-tile): bv0+bv1 read in p0,
//    held in regs; p1/p3 are read-free MFMA phases.
//  - delta 2: cvt kernels 8-wide (32B load / 16B store per thread).
// vmcnt LEDGER (2 gloads per stage macro; FIFO):
//   stage order in iter t (into buf[(t+1)&1]): p0:A0 p1:B0 p2:B1 p3:A1
//   steady state entering p0(t): outstanding = [A1(t)] (2)
//   p0: +A0(t+1) -> 4            (p0 reads A-half0,B-half0,B-half1 of t: all retired)
//   p1: +B0(t+1) -> 6; vmcnt(4) retires A1(t)   (p2 needs A-half1(t))
//   p2: +B1(t+1) -> 6            (reads A-half1(t): retired above)
//   p3: +A1(t+1) -> 8; vmcnt(2) retires A0,B0,B1(t+1) -> [A1(t+1)] = steady
//   last iter (no stages): p1-end vmcnt(0) drains A1(t).
//   WAR: stage targets in bufn were last ds_read >=2 barriers earlier. ✓
// ---------------------------------------------------------------------------

typedef __attribute__((ext_vector_type(8))) short short8;   // 8 x bf16
typedef __attribute__((ext_vector_type(4))) float f32x4;    // MFMA accum

#define B_SZ 4096
#define K_SZ 4096      // IN + H
#define N_SZ 8192      // 4*H
#define H_SZ 2048

typedef const __attribute__((address_space(1))) void gvoid_t;
typedef __attribute__((address_space(3))) void lvoid_t;

__device__ __forceinline__ void gload_lds16(const __hip_bfloat16* g, void* l) {
    // LDS dest is wave-uniform base; HW adds lane*16
    __builtin_amdgcn_global_load_lds((gvoid_t*)g, (lvoid_t*)l, 16, 0, 0);
}

__device__ __forceinline__ float hsig(float x) {
    return fminf(fmaxf(x * (1.0f / 6.0f) + 0.5f, 0.0f), 1.0f);
}
__device__ __forceinline__ float htanh(float x) {
    return fminf(fmaxf(x, -1.0f), 1.0f);
}

__device__ __forceinline__ void cvt8_store(const float* src, __hip_bfloat16* dst) {
    float4 v0 = *reinterpret_cast<const float4*>(src);
    float4 v1 = *reinterpret_cast<const float4*>(src + 4);
    union { __hip_bfloat16 h[8]; uint4 q; } p;
    p.h[0] = __float2bfloat16(v0.x); p.h[1] = __float2bfloat16(v0.y);
    p.h[2] = __float2bfloat16(v0.z); p.h[3] = __float2bfloat16(v0.w);
    p.h[4] = __float2bfloat16(v1.x); p.h[5] = __float2bfloat16(v1.y);
    p.h[6] = __float2bfloat16(v1.z); p.h[7] = __float2bfloat16(v1.w);
    *reinterpret_cast<uint4*>(dst) = p.q;
}

// ---- fp32 -> bf16 with [A | B] row-concat (for X' = [x | h]), 8-wide -------
__global__ void cvt_concat_kernel(const float* __restrict__ a,
                                  const float* __restrict__ b,
                                  __hip_bfloat16* __restrict__ out,
                                  int total8)
{
    int i = blockIdx.x * blockDim.x + threadIdx.x;
    if (i >= total8) return;
    int idx = i << 3;
    int r = idx >> 12;       // / 4096
    int c = idx & 4095;      // multiple of 8, never straddles the 2048 seam
    const float* src = (c < 2048) ? (a + (size_t)r * 2048 + c)
                                  : (b + (size_t)r * 2048 + (c - 2048));
    cvt8_store(src, out + idx);
}

// ---- W' builder: gate-interleaved row perm for the 256-wide tile, 8-wide ---
// GEMM col c (= out row r): bits [0:3]=fr, bit4=nf, bits[5:6]=wcol, bit7=nh,
// bits[8+]=bn. Gate = nh*2+nf = acc n-index; j = fr | wcol<<4 | bn<<6.
__global__ void cvt_w_perm_kernel(const float* __restrict__ wih,
                                  const float* __restrict__ whh,
                                  __hip_bfloat16* __restrict__ out,
                                  int total8)
{
    int i = blockIdx.x * blockDim.x + threadIdx.x;
    if (i >= total8) return;
    int idx = i << 3;
    int r = idx >> 12;        // out row 0..8191
    int c = idx & 4095;       // col, multiple of 8
    int gate = (((r >> 7) & 1) << 1) | ((r >> 4) & 1);
    int j = (r & 15) | (((r >> 5) & 3) << 4) | ((r >> 8) << 6);
    int srow = gate * 2048 + j;
    const float* src = (c < 2048) ? (wih + (size_t)srow * 2048 + c)
                                  : (whh + (size_t)srow * 2048 + (c - 2048));
    cvt8_store(src, out + idx);
}

// ---- fused GEMM + LSTM cell, 8-wave 256^2 counted-vmcnt schedule -----------
__global__ __launch_bounds__(512, 2)
void gemm_fused_kernel(const __hip_bfloat16* __restrict__ A,
                       const __hip_bfloat16* __restrict__ Bw,
                       const float* __restrict__ c0,
                       const float* __restrict__ bias,
                       float* __restrict__ out)
{
    constexpr int BK = 64;
    constexpr int NT = K_SZ / BK;            // 64 K-tiles
    constexpr int NWG = (B_SZ / 256) * (N_SZ / 256);  // 512
    constexpr int TILEB = 65536;             // A 32KB + B 32KB per buffer

    extern __shared__ __align__(16) char lds[];   // 2 * TILEB = 128KB dynamic

    const int tid  = threadIdx.x;
    const int wave = tid >> 6;
    const int lane = tid & 63;
    const int wrow = wave >> 2;        // 0..1
    const int wcol = wave & 3;         // 0..3
    const int fr   = lane & 15;
    const int fkq  = lane >> 4;

    // XCD-aware bijective swizzle (NWG = 512, %8==0)
    int bid = blockIdx.x;
    int swz = (bid & 7) * (NWG / 8) + (bid >> 3);
    int bm = swz >> 5;                 // 0..15
    int bn = swz & 31;                 // 0..31

    // ---- staging (linear LDS dest; inverse-swizzled global source) ---------
    const int rs  = tid >> 3;          // 0..63 row within 64-row stage
    const int ch  = tid & 7;
    const int lch = ch ^ (rs & 7);
    const __hip_bfloat16* pa = A  + (size_t)(bm * 256 + rs) * K_SZ + lch * 8;
    const __hip_bfloat16* pb = Bw + (size_t)(bn * 256 + rs) * K_SZ + lch * 8;

#define STG_A(bufn, kt, srow) \
    gload_lds16(pa + (size_t)(srow) * K_SZ + (kt), (bufn) + (srow) * 128 + wave * 1024)
#define STG_B(bufn, kt, srow) \
    gload_lds16(pb + (size_t)(srow) * K_SZ + (kt), (bufn) + 32768 + (srow) * 128 + wave * 1024)

    // ---- swizzled ds_read byte offsets (ks=0); ks=1 is ^64, mh/nh is +16384
    int a_off[4], b_off[2];
#pragma unroll
    for (int mf = 0; mf < 4; ++mf) {
        int row = wrow * 64 + mf * 16 + fr;
        a_off[mf] = row * 128 + ((fkq ^ (row & 7)) << 4);
    }
#pragma unroll
    for (int nf = 0; nf < 2; ++nf) {
        int row = wcol * 32 + nf * 16 + fr;
        b_off[nf] = row * 128 + ((fkq ^ (row & 7)) << 4);
    }

    f32x4 acc[8][4];
#pragma unroll
    for (int m = 0; m < 8; ++m)
#pragma unroll
        for (int n = 0; n < 4; ++n)
            acc[m][n] = f32x4{0.f, 0.f, 0.f, 0.f};

    // ---- prologue: stage tile 0 (order A0 B0 B1 A1), retire all but A1 -----
    {
        char* b0 = lds;
        STG_A(b0, 0, 0);   STG_A(b0, 0, 64);    // A-half0
        STG_B(b0, 0, 0);   STG_B(b0, 0, 64);    // B-half0
        STG_B(b0, 0, 128); STG_B(b0, 0, 192);   // B-half1
        STG_A(b0, 0, 128); STG_A(b0, 0, 192);   // A-half1
    }
    asm volatile("s_waitcnt vmcnt(2)" ::: "memory");   // A0,B0,B1 resident
    asm volatile("s_barrier" ::: "memory");

    short8 av[4][2], bv0[2][2], bv1[2][2];

#pragma unroll 1
    for (int t = 0; t < NT; ++t) {
        char* bufc = lds + (t & 1) * TILEB;
        char* bufn = lds + ((t + 1) & 1) * TILEB;
        const char* Ab = bufc;
        const char* Bb = bufc + 32768;
        const int ktn = (t + 1) * BK;
        const bool st = (t + 1 < NT);

        // ===== phase 0: reads {A-mh0, B-nh0, B-nh1}; MFMA (mh0,nh0) =====
#pragma unroll
        for (int mf = 0; mf < 4; ++mf)
#pragma unroll
            for (int ks = 0; ks < 2; ++ks)
                av[mf][ks] = *(const short8*)(Ab + (a_off[mf] ^ (ks << 6)));
#pragma unroll
        for (int nf = 0; nf < 2; ++nf)
#pragma unroll
            for (int ks = 0; ks < 2; ++ks) {
                bv0[nf][ks] = *(const short8*)(Bb + (b_off[nf] ^ (ks << 6)));
                bv1[nf][ks] = *(const short8*)(Bb + 16384 + (b_off[nf] ^ (ks << 6)));
            }
        if (st) { STG_A(bufn, ktn, 0); STG_A(bufn, ktn, 64); }
        asm volatile("s_barrier" ::: "memory");
        asm volatile("s_waitcnt lgkmcnt(0)" ::: "memory");
        __builtin_amdgcn_sched_barrier(0);
        __builtin_amdgcn_s_setprio(1);
#pragma unroll
        for (int mf = 0; mf < 4; ++mf)
#pragma unroll
            for (int nf = 0; nf < 2; ++nf)
#pragma unroll
                for (int ks = 0; ks < 2; ++ks)
                    acc[mf][nf] = __builtin_amdgcn_mfma_f32_16x16x32_bf16(av[mf][ks], bv0[nf][ks], acc[mf][nf], 0, 0, 0);
        __builtin_amdgcn_s_setprio(0);
        asm volatile("s_barrier" ::: "memory");

        // ===== phase 1 (read-free): MFMA (mh0,nh1) =====
        if (st) { STG_B(bufn, ktn, 0); STG_B(bufn, ktn, 64); }
        asm volatile("s_barrier" ::: "memory");
        __builtin_amdgcn_s_setprio(1);
#pragma unroll
        for (int mf = 0; mf < 4; ++mf)
#pragma unroll
            for (int nf = 0; nf < 2; ++nf)
#pragma unroll
                for (int ks = 0; ks < 2; ++ks)
                    acc[mf][2 + nf] = __builtin_amdgcn_mfma_f32_16x16x32_bf16(av[mf][ks], bv1[nf][ks], acc[mf][2 + nf], 0, 0, 0);
        __builtin_amdgcn_s_setprio(0);
        if (st) asm volatile("s_waitcnt vmcnt(4)" ::: "memory");  // retire A1(t)
        else    asm volatile("s_waitcnt vmcnt(0)" ::: "memory");
        asm volatile("s_barrier" ::: "memory");

        // ===== phase 2: reads {A-mh1}; MFMA (mh1,nh0) =====
#pragma unroll
        for (int mf = 0; mf < 4; ++mf)
#pragma unroll
            for (int ks = 0; ks < 2; ++ks)
                av[mf][ks] = *(const short8*)(Ab + 16384 + (a_off[mf] ^ (ks << 6)));
        if (st) { STG_B(bufn, ktn, 128); STG_B(bufn, ktn, 192); }
        asm volatile("s_barrier" ::: "memory");
        asm volatile("s_waitcnt lgkmcnt(0)" ::: "memory");
        __builtin_amdgcn_sched_barrier(0);
        __builtin_amdgcn_s_setprio(1);
#pragma unroll
        for (int mf = 0; mf < 4; ++mf)
#pragma unroll
            for (int nf = 0; nf < 2; ++nf)
#pragma unroll
                for (int ks = 0; ks < 2; ++ks)
                    acc[4 + mf][nf] = __builtin_amdgcn_mfma_f32_16x16x32_bf16(av[mf][ks], bv0[nf][ks], acc[4 + mf][nf], 0, 0, 0);
        __builtin_amdgcn_s_setprio(0);
        asm volatile("s_barrier" ::: "memory");

        // ===== phase 3 (read-free): MFMA (mh1,nh1) =====
        if (st) { STG_A(bufn, ktn, 128); STG_A(bufn, ktn, 192); }
        asm volatile("s_barrier" ::: "memory");
        __builtin_amdgcn_s_setprio(1);
#pragma unroll
        for (int mf = 0; mf < 4; ++mf)
#pragma unroll
            for (int nf = 0; nf < 2; ++nf)
#pragma unroll
                for (int ks = 0; ks < 2; ++ks)
                    acc[4 + mf][2 + nf] = __builtin_amdgcn_mfma_f32_16x16x32_bf16(av[mf][ks], bv1[nf][ks], acc[4 + mf][2 + nf], 0, 0, 0);
        __builtin_amdgcn_s_setprio(0);
        if (st) asm volatile("s_waitcnt vmcnt(2)" ::: "memory");  // retire A0,B0,B1(t+1)
        asm volatile("s_barrier" ::: "memory");
    }
#undef STG_A
#undef STG_B

    // ---- fused LSTM-cell epilogue (acc n-index == gate: 0=f,1=i,2=o,3=g) ---
    const int jj = bn * 64 + wcol * 16 + fr;         // 0..2047
    const float bf = bias[jj];
    const float bi = bias[2048 + jj];
    const float bo = bias[4096 + jj];
    const float bg = bias[6144 + jj];
    float* h1out = out;
    float* c1out = out + (size_t)B_SZ * H_SZ;
#pragma unroll
    for (int mh = 0; mh < 2; ++mh)
#pragma unroll
        for (int mf = 0; mf < 4; ++mf) {
            const int m = mh * 4 + mf;
            const int row0 = bm * 256 + mh * 128 + wrow * 64 + mf * 16 + fkq * 4;
#pragma unroll
            for (int i = 0; i < 4; ++i) {
                int r = row0 + i;
                float c0v = c0[(size_t)r * H_SZ + jj];
                float f  = acc[m][0][i] + bf;
                float ig = acc[m][1][i] + bi;
                float o  = acc[m][2][i] + bo;
                float g  = acc[m][3][i] + bg;
                float cn = hsig(f) * c0v + hsig(ig) * htanh(g);
                h1out[(size_t)r * H_SZ + jj] = hsig(o) * htanh(cn);
                c1out[(size_t)r * H_SZ + jj] = cn;
            }
        }
}

// ---------------------------------------------------------------------------
extern "C" void kernel_launch(void* const* d_in, const int* in_sizes, int n_in,
                              void* d_out, int out_size, void* d_ws, size_t ws_size,
                              hipStream_t stream)
{
    const float* x   = (const float*)d_in[0];  // [4096,2048]
    const float* h0  = (const float*)d_in[1];  // [4096,2048]
    const float* c0  = (const float*)d_in[2];  // [4096,2048]
    const float* Wih = (const float*)d_in[3];  // [8192,2048]
    const float* Whh = (const float*)d_in[4];  // [8192,2048]
    const float* bhh = (const float*)d_in[5];  // [8192]
    float* out = (float*)d_out;                // h1 (8M) ++ c1 (8M) fp32

    // workspace: X' bf16 32MB | W' bf16 64MB
    if (ws_size < (size_t)96 * 1024 * 1024) return;
    char* ws = (char*)d_ws;
    __hip_bfloat16* Xp = (__hip_bfloat16*)ws;
    __hip_bfloat16* Wp = (__hip_bfloat16*)(ws + (size_t)32 * 1024 * 1024);

    int t8x = B_SZ * K_SZ / 8;   // 2M
    cvt_concat_kernel<<<t8x / 256, 256, 0, stream>>>(x, h0, Xp, t8x);
    int t8w = N_SZ * K_SZ / 8;   // 4M
    cvt_w_perm_kernel<<<t8w / 256, 256, 0, stream>>>(Wih, Whh, Wp, t8w);

    gemm_fused_kernel<<<512, 512, 131072, stream>>>(Xp, Wp, c0, bhh, out);
}